// Round 3
// baseline (460.926 us; speedup 1.0000x reference)
//
#include <hip/hip_runtime.h>

// B=4, C=256, C8=32, N=4096. fp16 MFMA: 16x16x32 (proj), 32x32x16 (S + PV).
#define BB 4
#define CC 256
#define NN 4096

typedef _Float16 half_t;
typedef __attribute__((ext_vector_type(8))) _Float16 half8;
typedef __attribute__((ext_vector_type(4))) _Float16 half4;
typedef __attribute__((ext_vector_type(4))) float floatx4;
typedef __attribute__((ext_vector_type(16))) float floatx16;
typedef __attribute__((ext_vector_type(2))) unsigned int uint2v;

union H2U { _Float16 h[2]; unsigned int u; };
union U4H8 { unsigned int u[4]; half8 v; };

// ---------------------------------------------------------------------------
// cvt_w: cast the six weight matrices to fp16. grid (64, 6).
// ---------------------------------------------------------------------------
__global__ __launch_bounds__(256)
void cvt_w_kernel(const float* __restrict__ Wfx, const float* __restrict__ Wgx,
                  const float* __restrict__ Whx, const float* __restrict__ Wfy,
                  const float* __restrict__ Wgy, const float* __restrict__ Why,
                  half_t* __restrict__ oWfx, half_t* __restrict__ oWgx,
                  half_t* __restrict__ oWhx, half_t* __restrict__ oWfy,
                  half_t* __restrict__ oWgy, half_t* __restrict__ oWhy)
{
    const float* src; half_t* dst; int n;
    switch (blockIdx.y) {
        case 0: src = Wfx; dst = oWfx; n = 32 * CC; break;
        case 1: src = Wgx; dst = oWgx; n = 32 * CC; break;
        case 2: src = Whx; dst = oWhx; n = CC * CC; break;
        case 3: src = Wfy; dst = oWfy; n = 32 * CC; break;
        case 4: src = Wgy; dst = oWgy; n = 32 * CC; break;
        default: src = Why; dst = oWhy; n = CC * CC; break;
    }
    int idx = (blockIdx.x * 256 + threadIdx.x) * 4;
    if (idx >= n) return;
    float4 v = *(const float4*)&src[idx];
    half4 h; h[0] = (half_t)v.x; h[1] = (half_t)v.y; h[2] = (half_t)v.z; h[3] = (half_t)v.w;
    *(half4*)&dst[idx] = h;
}

// ---------------------------------------------------------------------------
// transpose_cvt: xT[b][n][c] fp16 from in[b][c][n] fp32. grid (64, 4, 8).
// ---------------------------------------------------------------------------
__global__ __launch_bounds__(256)
void transpose_cvt_kernel(const float* __restrict__ x, const float* __restrict__ y,
                          half_t* __restrict__ xTx, half_t* __restrict__ xTy)
{
    const int n0 = blockIdx.x * 64;
    const int c0 = blockIdx.y * 64;
    const int b  = blockIdx.z & 3;
    const int sel = blockIdx.z >> 2;
    const float* in = sel ? y : x;
    half_t* outT = sel ? xTy : xTx;
    const int t  = threadIdx.x;
    const int ch = t & 7, nl = t >> 3;            // 8 c-chunks x 32 n
    const float* inb = in + (size_t)b * CC * NN;
    half_t* outb = outT + (size_t)b * NN * CC;

    #pragma unroll
    for (int p = 0; p < 2; ++p) {
        int n = n0 + nl + 32 * p;
        half8 hv;
        #pragma unroll
        for (int j = 0; j < 8; ++j)
            hv[j] = (half_t)inb[(size_t)(c0 + 8 * ch + j) * NN + n];
        *(half8*)&outb[(size_t)n * CC + c0 + 8 * ch] = hv;
    }
}

// ---------------------------------------------------------------------------
// proj_fg (MFMA): fT[n][32], gT[n][32]. grid (64, 4, 2): z = sel.
// ---------------------------------------------------------------------------
__global__ __launch_bounds__(256)
void proj_fg_kernel(const half_t* __restrict__ xTx, const half_t* __restrict__ xTy,
                    const half_t* __restrict__ Wfx, const half_t* __restrict__ Wgx,
                    const half_t* __restrict__ Wfy, const half_t* __restrict__ Wgy,
                    const float* __restrict__ bfx, const float* __restrict__ bgx,
                    const float* __restrict__ bfy, const float* __restrict__ bgy,
                    half_t* __restrict__ fxT, half_t* __restrict__ gxT,
                    half_t* __restrict__ fyT, half_t* __restrict__ gyT)
{
    const int n0 = blockIdx.x * 64;
    const int b  = blockIdx.y;
    const int sel = blockIdx.z;
    const half_t* xT = sel ? xTy : xTx;
    const half_t* Wf = sel ? Wfy : Wfx;
    const half_t* Wg = sel ? Wgy : Wgx;
    const float*  bf = sel ? bfy : bfx;
    const float*  bg = sel ? bgy : bgx;
    half_t* fT = sel ? fyT : fxT;
    half_t* gT = sel ? gyT : gxT;

    const int t  = threadIdx.x;
    const int w = t >> 6, lane = t & 63, q = lane >> 4, mc = lane & 15;
    const half_t* xTb = xT + (size_t)b * NN * CC;

    floatx4 acc[4];
    #pragma unroll
    for (int i = 0; i < 4; ++i) {
        float bv = (i < 2 ? bf : bg)[(i & 1) * 16 + mc];
        acc[i] = (floatx4){bv, bv, bv, bv};
    }

    #pragma unroll
    for (int ks = 0; ks < 8; ++ks) {
        int k0 = ks * 32 + q * 8;
        half8 af = *(const half8*)&xTb[(size_t)(n0 + w * 16 + mc) * CC + k0];
        #pragma unroll
        for (int i = 0; i < 4; ++i) {
            const half_t* Ws = (i < 2) ? Wf : Wg;
            half8 bfr = *(const half8*)&Ws[(size_t)((i & 1) * 16 + mc) * CC + k0];
            acc[i] = __builtin_amdgcn_mfma_f32_16x16x32_f16(af, bfr, acc[i], 0, 0, 0);
        }
    }

    #pragma unroll
    for (int i = 0; i < 4; ++i) {
        half_t* dst = (i < 2) ? fT : gT;
        #pragma unroll
        for (int r = 0; r < 4; ++r) {
            int n = n0 + w * 16 + q * 4 + r;
            dst[((size_t)b * NN + n) * 32 + (i & 1) * 16 + mc] = (half_t)acc[i][r];
        }
    }
}

// ---------------------------------------------------------------------------
// proj_h (MFMA): h[o][n] plain layout (R4-verified). grid (64, 2, 8).
// ---------------------------------------------------------------------------
__global__ __launch_bounds__(256)
void proj_h_kernel(const half_t* __restrict__ xTx, const half_t* __restrict__ xTy,
                   const half_t* __restrict__ Whx, const half_t* __restrict__ Why,
                   const float* __restrict__ bhx, const float* __restrict__ bhy,
                   half_t* __restrict__ hx, half_t* __restrict__ hy)
{
    const int n0 = blockIdx.x * 64;
    const int o0 = blockIdx.y * 128;
    const int b  = blockIdx.z & 3;
    const int sel = blockIdx.z >> 2;
    const half_t* xT = sel ? xTy : xTx;
    const half_t* Wh = sel ? Why : Whx;
    const float*  bh = sel ? bhy : bhx;
    half_t* h = sel ? hy : hx;

    const int t  = threadIdx.x;
    const int w = t >> 6, lane = t & 63, q = lane >> 4, mc = lane & 15;
    const half_t* xTb = xT + (size_t)b * NN * CC;
    half_t* hb = h + (size_t)b * CC * NN;

    floatx4 acc[2][4];
    #pragma unroll
    for (int j = 0; j < 2; ++j) {
        floatx4 bv;
        #pragma unroll
        for (int r = 0; r < 4; ++r) bv[r] = bh[o0 + w * 32 + j * 16 + q * 4 + r];
        #pragma unroll
        for (int i = 0; i < 4; ++i) acc[j][i] = bv;
    }

    #pragma unroll
    for (int ks = 0; ks < 8; ++ks) {
        int k0 = ks * 32 + q * 8;
        half8 a0 = *(const half8*)&Wh[(size_t)(o0 + w * 32 + mc) * CC + k0];
        half8 a1 = *(const half8*)&Wh[(size_t)(o0 + w * 32 + 16 + mc) * CC + k0];
        #pragma unroll
        for (int i = 0; i < 4; ++i) {
            half8 bfr = *(const half8*)&xTb[(size_t)(n0 + i * 16 + mc) * CC + k0];
            acc[0][i] = __builtin_amdgcn_mfma_f32_16x16x32_f16(a0, bfr, acc[0][i], 0, 0, 0);
            acc[1][i] = __builtin_amdgcn_mfma_f32_16x16x32_f16(a1, bfr, acc[1][i], 0, 0, 0);
        }
    }

    #pragma unroll
    for (int j = 0; j < 2; ++j)
        #pragma unroll
        for (int i = 0; i < 4; ++i)
            #pragma unroll
            for (int r = 0; r < 4; ++r) {
                int o = o0 + w * 32 + j * 16 + q * 4 + r;
                hb[(size_t)o * NN + n0 + i * 16 + mc] = (half_t)acc[j][i][r];
            }
}

// ---------------------------------------------------------------------------
// stats: Llog2[n] = -log2( sum_m exp(S[n,m]) ). grid (128, 4, 2).
// ---------------------------------------------------------------------------
__global__ __launch_bounds__(256)
void stats_kernel(const half_t* __restrict__ fT0, const half_t* __restrict__ gT0,
                  const half_t* __restrict__ fT1, const half_t* __restrict__ gT1,
                  float* __restrict__ L0, float* __restrict__ L1)
{
    __shared__ float red_l[4][32];
    const int b  = blockIdx.y;
    const int sel = blockIdx.z;
    const half_t* fT = sel ? fT1 : fT0;
    const half_t* gT = sel ? gT1 : gT0;
    float* Lout = sel ? L1 : L0;

    const int n0 = blockIdx.x * 32;
    const int t  = threadIdx.x;
    const int w = t >> 6, lane = t & 63, q = lane >> 4, mc = lane & 15;
    const half_t* fTb = fT + (size_t)b * NN * 32;
    const half_t* gTb = gT + (size_t)b * NN * 32;

    half8 a0 = *(const half8*)&fTb[(size_t)(n0 + mc) * 32 + q * 8];
    half8 a1 = *(const half8*)&fTb[(size_t)(n0 + 16 + mc) * 32 + q * 8];

    float l0[4] = {0.f, 0.f, 0.f, 0.f}, l1[4] = {0.f, 0.f, 0.f, 0.f};
    for (int it = 0; it < NN / 64; ++it) {
        int m = (it * 4 + w) * 16 + mc;
        half8 bfr = *(const half8*)&gTb[(size_t)m * 32 + q * 8];
        floatx4 S0 = __builtin_amdgcn_mfma_f32_16x16x32_f16(a0, bfr, (floatx4){0.f,0.f,0.f,0.f}, 0, 0, 0);
        floatx4 S1 = __builtin_amdgcn_mfma_f32_16x16x32_f16(a1, bfr, (floatx4){0.f,0.f,0.f,0.f}, 0, 0, 0);
        #pragma unroll
        for (int r = 0; r < 4; ++r) { l0[r] += __expf(S0[r]); l1[r] += __expf(S1[r]); }
    }
    #pragma unroll
    for (int r = 0; r < 4; ++r) {
        #pragma unroll
        for (int off = 1; off < 16; off <<= 1) {
            l0[r] += __shfl_xor(l0[r], off);
            l1[r] += __shfl_xor(l1[r], off);
        }
    }
    if (mc == 0)
        #pragma unroll
        for (int r = 0; r < 4; ++r) {
            red_l[w][q * 4 + r]      = l0[r];
            red_l[w][16 + q * 4 + r] = l1[r];
        }
    __syncthreads();
    if (t < 32) {
        float L = red_l[0][t] + red_l[1][t] + red_l[2][t] + red_l[3][t];
        Lout[(size_t)b * NN + n0 + t] = -log2f(L);
    }
}

// ---------------------------------------------------------------------------
// pv: out[c,m] = src[c,m] + gamma * sum_n h[c,n] * exp2(S*log2e + Llog2[n]).
// v4: cross-iteration software pipeline. Same math/layout as v3 (verified):
// wave w: m-quarter mq=(w&3)*32, n-half nh=(w>>2)*32; S swapped-MFMA32 ->
// in-reg exp -> pack -> permlane32_swap -> PV B-frags; h_lds XOR-swizzled,
// double-buffered, one barrier/iter; pair (w,w+4) partials reduced at end.
// NEW schedule per tile T (parity par=T&1, macros keep indices static):
//   LOADS(T+2->slot par) ; S-MFMA(T+1, slot par^1) issue ;
//   PV(T) [hides S latency] ; exp/pack(T+1) [VALU overlaps MFMA drain] ;
//   stage h(T+1) ; barrier.
// Loads land a full iteration before use; P(T+1) compute overlaps PV(T).
// ---------------------------------------------------------------------------
__global__ __launch_bounds__(512, 4)
void pv_kernel(const half_t* __restrict__ fT0, const half_t* __restrict__ gT0,
               const half_t* __restrict__ h0, const float* __restrict__ L0,
               const float* __restrict__ src0, float* __restrict__ out0,
               const half_t* __restrict__ fT1, const half_t* __restrict__ gT1,
               const half_t* __restrict__ h1, const float* __restrict__ L1,
               const float* __restrict__ src1, float* __restrict__ out1,
               const float* __restrict__ gamma)
{
    __shared__ half_t h_lds[2][128][64];   // 32 KB, XOR-chunk swizzled

    const int m0 = blockIdx.x * 128;
    const int c0 = blockIdx.y * 128;
    const int b  = blockIdx.z & 3;
    const int sel = blockIdx.z >> 2;
    const half_t* fT = sel ? fT1 : fT0;
    const half_t* gT = sel ? gT1 : gT0;
    const half_t* h  = sel ? h1 : h0;
    const float*  Lg = sel ? L1 : L0;
    const float*  src = sel ? src1 : src0;
    float* out = sel ? out1 : out0;

    const int t = threadIdx.x;
    const int w = t >> 6, lane = t & 63;
    const int l5 = lane >> 5, l31 = lane & 31;
    const int mq  = (w & 3) * 32;      // wave's m-quarter
    const int nh  = (w >> 2) * 32;     // wave's n-half within 64-tile
    const int nh8 = nh >> 3;           // 16B-chunk offset of n-half

    const half_t* fTb = fT + (size_t)b * NN * 32;
    const half_t* gTb = gT + (size_t)b * NN * 32;
    const half_t* hb  = h + (size_t)b * CC * NN;
    const float*  Lb  = Lg + (size_t)b * NN;

    // persistent S B-frags (g): col m = m0+mq+l31, k-chunks [0,16) and [16,32)
    const half8 gS0 = *(const half8*)&gTb[(size_t)(m0 + mq + l31) * 32 + l5 * 8];
    const half8 gS1 = *(const half8*)&gTb[(size_t)(m0 + mq + l31) * 32 + 16 + l5 * 8];

    // h staging: thread covers rows {sr, sr+64}; LDS slot sj holds global
    // chunk sj^(row&7) (pre-swizzled source; (sr+64)&7 == sr&7).
    const int sj  = t & 7;
    const int sr  = t >> 3;            // 0..63
    const int sjx = sj ^ (sr & 7);

    // pipeline base pointers (32-bit offsets off these)
    const half_t* hpr0 = hb + (size_t)(c0 + sr) * NN + sjx * 8;
    const half_t* hpr1 = hb + (size_t)(c0 + sr + 64) * NN + sjx * 8;
    const half_t* fpr  = fTb + (size_t)(nh + l31) * 32;
    const float*  lpr  = Lb + nh;

    floatx16 acc[4];
    #pragma unroll
    for (int s = 0; s < 4; ++s)
        #pragma unroll
        for (int r = 0; r < 16; ++r) acc[s][r] = 0.f;

    floatx16 Zc;
    #pragma unroll
    for (int r = 0; r < 16; ++r) Zc[r] = 0.f;

    // pipeline registers: slot 0/1 (tile parity), all statically indexed
    half8 hg00, hg01, hg10, hg11;          // hg<slot><row-half>
    half8 af00, af01, af10, af11;          // af<slot><k-chunk>
    floatx4 lv0[4], lv1[4];
    half8 Bf00, Bf01, Bf10, Bf11;          // Bf<parity><k-chunk>
    floatx16 Sreg;

#define LOADS(s, TT) {                                                        \
    const int o_ = (TT) * 64;                                                 \
    hg##s##0 = *(const half8*)&hpr0[o_];                                      \
    hg##s##1 = *(const half8*)&hpr1[o_];                                      \
    af##s##0 = *(const half8*)&fpr[(size_t)o_ * 32 + l5 * 8];                 \
    af##s##1 = *(const half8*)&fpr[(size_t)o_ * 32 + 16 + l5 * 8];            \
    _Pragma("unroll")                                                         \
    for (int g_ = 0; g_ < 4; ++g_)                                            \
        lv##s[g_] = *(const floatx4*)&lpr[o_ + 8 * g_ + 4 * l5];              \
}

#define SMM(s) {                                                              \
    Sreg = __builtin_amdgcn_mfma_f32_32x32x16_f16(af##s##0, gS0, Zc, 0, 0, 0);\
    Sreg = __builtin_amdgcn_mfma_f32_32x32x16_f16(af##s##1, gS1, Sreg, 0, 0, 0);\
}

#define EXPPK(s) {                                                            \
    float p_[16];                                                             \
    _Pragma("unroll")                                                         \
    for (int g_ = 0; g_ < 4; ++g_)                                            \
        _Pragma("unroll")                                                     \
        for (int j_ = 0; j_ < 4; ++j_)                                        \
            p_[g_ * 4 + j_] = exp2f(fmaf(Sreg[g_ * 4 + j_], 1.44269504f,      \
                                         lv##s[g_][j_]));                     \
    unsigned int pk_[8];                                                      \
    _Pragma("unroll")                                                         \
    for (int j_ = 0; j_ < 8; ++j_) {                                          \
        H2U x_; x_.h[0] = (half_t)p_[2 * j_]; x_.h[1] = (half_t)p_[2 * j_ + 1];\
        pk_[j_] = x_.u;                                                       \
    }                                                                         \
    uint2v s0_ = __builtin_amdgcn_permlane32_swap(pk_[0], pk_[2], false, false);\
    uint2v s1_ = __builtin_amdgcn_permlane32_swap(pk_[1], pk_[3], false, false);\
    uint2v s2_ = __builtin_amdgcn_permlane32_swap(pk_[4], pk_[6], false, false);\
    uint2v s3_ = __builtin_amdgcn_permlane32_swap(pk_[5], pk_[7], false, false);\
    U4H8 f0_, f1_;                                                            \
    f0_.u[0] = s0_.x; f0_.u[1] = s1_.x; f0_.u[2] = s0_.y; f0_.u[3] = s1_.y;   \
    f1_.u[0] = s2_.x; f1_.u[1] = s3_.x; f1_.u[2] = s2_.y; f1_.u[3] = s3_.y;   \
    Bf##s##0 = f0_.v; Bf##s##1 = f1_.v;                                       \
}

#define PVM(par) {                                                            \
    _Pragma("unroll")                                                         \
    for (int K_ = 0; K_ < 2; ++K_) {                                          \
        const half8 Bq_ = K_ ? Bf##par##1 : Bf##par##0;                       \
        const int cidx_ = (((nh8 + 2 * K_ + l5) ^ (l31 & 7)) << 3);           \
        _Pragma("unroll")                                                     \
        for (int s_ = 0; s_ < 4; ++s_) {                                      \
            half8 Ah_ = *(const half8*)&h_lds[par][s_ * 32 + l31][cidx_];     \
            acc[s_] = __builtin_amdgcn_mfma_f32_32x32x16_f16(Ah_, Bq_,        \
                                                             acc[s_], 0, 0, 0);\
        }                                                                     \
    }                                                                         \
}

#define STAGE(s, buf) {                                                       \
    *(half8*)&h_lds[buf][sr][sj * 8]      = hg##s##0;                         \
    *(half8*)&h_lds[buf][sr + 64][sj * 8] = hg##s##1;                         \
}

#define BODY(par, opp, T) {                                                   \
    LOADS(par, ((T) + 2) & 63);   /* tile T+2 -> freed slot par */            \
    SMM(opp);                     /* S(T+1) issue; latency hidden by PV */    \
    PVM(par);                     /* PV(T): ds_read + 8 MFMA */               \
    EXPPK(opp);                   /* exp/pack(T+1) -> Bf[opp] */              \
    STAGE(opp, opp);              /* h(T+1) -> h_lds[opp] */                  \
    __syncthreads();                                                          \
}

    // ---- prologue: tiles 0 and 1 in flight; P(0) + h_lds[0] ready
    LOADS(0, 0);
    LOADS(1, 1);
    SMM(0);
    EXPPK(0);
    STAGE(0, 0);
    __syncthreads();

    for (int T = 0; T < NN / 64; T += 2) {
        BODY(0, 1, T);
        BODY(1, 0, T + 1);
    }
    // (final BODY computes one wasted S/exp for wrapped tile; never consumed)

#undef LOADS
#undef SMM
#undef EXPPK
#undef PVM
#undef STAGE
#undef BODY

    // ---- pair reduction: wave w (nh=0) += wave w+4 (nh=32), via LDS (17-pad)
    float* red = (float*)&h_lds[0][0][0];      // reuse 32 KB
    #pragma unroll
    for (int s = 0; s < 4; ++s) {
        __syncthreads();
        if (w >= 4) {
            float* dst = &red[(size_t)((w - 4) * 64 + lane) * 17];
            #pragma unroll
            for (int r = 0; r < 16; ++r) dst[r] = acc[s][r];
        }
        __syncthreads();
        if (w < 4) {
            const float* s2 = &red[(size_t)(w * 64 + lane) * 17];
            #pragma unroll
            for (int r = 0; r < 16; ++r) acc[s][r] += s2[r];
        }
    }

    // ---- epilogue (lower waves): out = src + gamma * acc
    if (w < 4) {
        const float gm = gamma[0];
        const float* srcb = src + (size_t)b * CC * NN;
        float* outb = out + (size_t)b * CC * NN;
        const int m = m0 + w * 32 + l31;
        #pragma unroll
        for (int s = 0; s < 4; ++s)
            #pragma unroll
            for (int r = 0; r < 16; ++r) {
                int c = c0 + s * 32 + (r & 3) + 8 * (r >> 2) + 4 * l5;
                size_t idx = (size_t)c * NN + m;
                outb[idx] = fmaf(gm, acc[s][r], srcb[idx]);
            }
    }
}

// ---------------------------------------------------------------------------
extern "C" void kernel_launch(void* const* d_in, const int* in_sizes, int n_in,
                              void* d_out, int out_size, void* d_ws, size_t ws_size,
                              hipStream_t stream)
{
    const float* x   = (const float*)d_in[0];
    const float* y   = (const float*)d_in[1];
    const float* Wfx = (const float*)d_in[2];
    const float* bfx = (const float*)d_in[3];
    const float* Wgx = (const float*)d_in[4];
    const float* bgx = (const float*)d_in[5];
    const float* Whx = (const float*)d_in[6];
    const float* bhx = (const float*)d_in[7];
    const float* Wfy = (const float*)d_in[8];
    const float* bfy = (const float*)d_in[9];
    const float* Wgy = (const float*)d_in[10];
    const float* bgy = (const float*)d_in[11];
    const float* Why = (const float*)d_in[12];
    const float* bhy = (const float*)d_in[13];
    const float* gam = (const float*)d_in[14];

    const size_t SZ_XT = (size_t)BB * NN * CC;   // 4,194,304 halves
    const size_t SZ_FG = (size_t)BB * NN * 32;   // 524,288 halves
    half_t* xTx   = (half_t*)d_ws;
    half_t* xTy   = xTx + SZ_XT;
    half_t* hx    = xTy + SZ_XT;
    half_t* hy    = hx + SZ_XT;
    half_t* fxT   = hy + SZ_XT;
    half_t* gxT   = fxT + SZ_FG;
    half_t* fyT   = gxT + SZ_FG;
    half_t* gyT   = fyT + SZ_FG;
    half_t* Wfx_h = gyT + SZ_FG;
    half_t* Wgx_h = Wfx_h + 32 * CC;
    half_t* Wfy_h = Wgx_h + 32 * CC;
    half_t* Wgy_h = Wfy_h + 32 * CC;
    half_t* Whx_h = Wgy_h + 32 * CC;
    half_t* Why_h = Whx_h + CC * CC;
    float*  Lx    = (float*)(Why_h + CC * CC);
    float*  Ly    = Lx + (size_t)BB * NN;

    float* outx = (float*)d_out;
    float* outy = outx + (size_t)BB * CC * NN;

    cvt_w_kernel<<<dim3(64, 6), 256, 0, stream>>>(Wfx, Wgx, Whx, Wfy, Wgy, Why,
                                                  Wfx_h, Wgx_h, Whx_h, Wfy_h, Wgy_h, Why_h);

    transpose_cvt_kernel<<<dim3(64, 4, 8), 256, 0, stream>>>(x, y, xTx, xTy);

    proj_fg_kernel<<<dim3(64, 4, 2), 256, 0, stream>>>(
        xTx, xTy, Wfx_h, Wgx_h, Wfy_h, Wgy_h, bfx, bgx, bfy, bgy, fxT, gxT, fyT, gyT);

    proj_h_kernel<<<dim3(64, 2, 8), 256, 0, stream>>>(
        xTx, xTy, Whx_h, Why_h, bhx, bhy, hx, hy);

    // att_x rows: fy vs gx -> Lx ; att_y rows: fx vs gy -> Ly
    stats_kernel<<<dim3(128, 4, 2), 256, 0, stream>>>(fyT, gxT, fxT, gyT, Lx, Ly);

    pv_kernel<<<dim3(32, 2, 8), 512, 0, stream>>>(
        fyT, gxT, hx, Lx, x, outx,
        fxT, gyT, hy, Ly, y, outy, gam);
}

// Round 4
// 281.402 us; speedup vs baseline: 1.6380x; 1.6380x over previous
//
#include <hip/hip_runtime.h>

// B=4, C=256, C8=32, N=4096. fp16 MFMA: 16x16x32 (S, proj), 32x32x16 (PV).
#define BB 4
#define CC 256
#define NN 4096

typedef _Float16 half_t;
typedef __attribute__((ext_vector_type(8))) _Float16 half8;
typedef __attribute__((ext_vector_type(4))) _Float16 half4;
typedef __attribute__((ext_vector_type(4))) float floatx4;
typedef __attribute__((ext_vector_type(16))) float floatx16;

// ---------------------------------------------------------------------------
// cvt_w: cast the six weight matrices to fp16. grid (64, 6).
// ---------------------------------------------------------------------------
__global__ __launch_bounds__(256)
void cvt_w_kernel(const float* __restrict__ Wfx, const float* __restrict__ Wgx,
                  const float* __restrict__ Whx, const float* __restrict__ Wfy,
                  const float* __restrict__ Wgy, const float* __restrict__ Why,
                  half_t* __restrict__ oWfx, half_t* __restrict__ oWgx,
                  half_t* __restrict__ oWhx, half_t* __restrict__ oWfy,
                  half_t* __restrict__ oWgy, half_t* __restrict__ oWhy)
{
    const float* src; half_t* dst; int n;
    switch (blockIdx.y) {
        case 0: src = Wfx; dst = oWfx; n = 32 * CC; break;
        case 1: src = Wgx; dst = oWgx; n = 32 * CC; break;
        case 2: src = Whx; dst = oWhx; n = CC * CC; break;
        case 3: src = Wfy; dst = oWfy; n = 32 * CC; break;
        case 4: src = Wgy; dst = oWgy; n = 32 * CC; break;
        default: src = Why; dst = oWhy; n = CC * CC; break;
    }
    int idx = (blockIdx.x * 256 + threadIdx.x) * 4;
    if (idx >= n) return;
    float4 v = *(const float4*)&src[idx];
    half4 h; h[0] = (half_t)v.x; h[1] = (half_t)v.y; h[2] = (half_t)v.z; h[3] = (half_t)v.w;
    *(half4*)&dst[idx] = h;
}

// ---------------------------------------------------------------------------
// transpose_cvt: xT[b][n][c] fp16 from in[b][c][n] fp32. grid (64, 4, 8).
// ---------------------------------------------------------------------------
__global__ __launch_bounds__(256)
void transpose_cvt_kernel(const float* __restrict__ x, const float* __restrict__ y,
                          half_t* __restrict__ xTx, half_t* __restrict__ xTy)
{
    const int n0 = blockIdx.x * 64;
    const int c0 = blockIdx.y * 64;
    const int b  = blockIdx.z & 3;
    const int sel = blockIdx.z >> 2;
    const float* in = sel ? y : x;
    half_t* outT = sel ? xTy : xTx;
    const int t  = threadIdx.x;
    const int ch = t & 7, nl = t >> 3;            // 8 c-chunks x 32 n
    const float* inb = in + (size_t)b * CC * NN;
    half_t* outb = outT + (size_t)b * NN * CC;

    #pragma unroll
    for (int p = 0; p < 2; ++p) {
        int n = n0 + nl + 32 * p;
        half8 hv;
        #pragma unroll
        for (int j = 0; j < 8; ++j)
            hv[j] = (half_t)inb[(size_t)(c0 + 8 * ch + j) * NN + n];
        *(half8*)&outb[(size_t)n * CC + c0 + 8 * ch] = hv;
    }
}

// ---------------------------------------------------------------------------
// proj_fg (MFMA): fT[n][32], gT[n][32]. grid (64, 4, 2): z = sel.
// ---------------------------------------------------------------------------
__global__ __launch_bounds__(256)
void proj_fg_kernel(const half_t* __restrict__ xTx, const half_t* __restrict__ xTy,
                    const half_t* __restrict__ Wfx, const half_t* __restrict__ Wgx,
                    const half_t* __restrict__ Wfy, const half_t* __restrict__ Wgy,
                    const float* __restrict__ bfx, const float* __restrict__ bgx,
                    const float* __restrict__ bfy, const float* __restrict__ bgy,
                    half_t* __restrict__ fxT, half_t* __restrict__ gxT,
                    half_t* __restrict__ fyT, half_t* __restrict__ gyT)
{
    const int n0 = blockIdx.x * 64;
    const int b  = blockIdx.y;
    const int sel = blockIdx.z;
    const half_t* xT = sel ? xTy : xTx;
    const half_t* Wf = sel ? Wfy : Wfx;
    const half_t* Wg = sel ? Wgy : Wgx;
    const float*  bf = sel ? bfy : bfx;
    const float*  bg = sel ? bgy : bgx;
    half_t* fT = sel ? fyT : fxT;
    half_t* gT = sel ? gyT : gxT;

    const int t  = threadIdx.x;
    const int w = t >> 6, lane = t & 63, q = lane >> 4, mc = lane & 15;
    const half_t* xTb = xT + (size_t)b * NN * CC;

    floatx4 acc[4];
    #pragma unroll
    for (int i = 0; i < 4; ++i) {
        float bv = (i < 2 ? bf : bg)[(i & 1) * 16 + mc];
        acc[i] = (floatx4){bv, bv, bv, bv};
    }

    #pragma unroll
    for (int ks = 0; ks < 8; ++ks) {
        int k0 = ks * 32 + q * 8;
        half8 af = *(const half8*)&xTb[(size_t)(n0 + w * 16 + mc) * CC + k0];
        #pragma unroll
        for (int i = 0; i < 4; ++i) {
            const half_t* Ws = (i < 2) ? Wf : Wg;
            half8 bfr = *(const half8*)&Ws[(size_t)((i & 1) * 16 + mc) * CC + k0];
            acc[i] = __builtin_amdgcn_mfma_f32_16x16x32_f16(af, bfr, acc[i], 0, 0, 0);
        }
    }

    #pragma unroll
    for (int i = 0; i < 4; ++i) {
        half_t* dst = (i < 2) ? fT : gT;
        #pragma unroll
        for (int r = 0; r < 4; ++r) {
            int n = n0 + w * 16 + q * 4 + r;
            dst[((size_t)b * NN + n) * 32 + (i & 1) * 16 + mc] = (half_t)acc[i][r];
        }
    }
}

// ---------------------------------------------------------------------------
// proj_h (MFMA): h[o][n] plain layout (R4-verified). grid (64, 2, 8).
// ---------------------------------------------------------------------------
__global__ __launch_bounds__(256)
void proj_h_kernel(const half_t* __restrict__ xTx, const half_t* __restrict__ xTy,
                   const half_t* __restrict__ Whx, const half_t* __restrict__ Why,
                   const float* __restrict__ bhx, const float* __restrict__ bhy,
                   half_t* __restrict__ hx, half_t* __restrict__ hy)
{
    const int n0 = blockIdx.x * 64;
    const int o0 = blockIdx.y * 128;
    const int b  = blockIdx.z & 3;
    const int sel = blockIdx.z >> 2;
    const half_t* xT = sel ? xTy : xTx;
    const half_t* Wh = sel ? Why : Whx;
    const float*  bh = sel ? bhy : bhx;
    half_t* h = sel ? hy : hx;

    const int t  = threadIdx.x;
    const int w = t >> 6, lane = t & 63, q = lane >> 4, mc = lane & 15;
    const half_t* xTb = xT + (size_t)b * NN * CC;
    half_t* hb = h + (size_t)b * CC * NN;

    floatx4 acc[2][4];
    #pragma unroll
    for (int j = 0; j < 2; ++j) {
        floatx4 bv;
        #pragma unroll
        for (int r = 0; r < 4; ++r) bv[r] = bh[o0 + w * 32 + j * 16 + q * 4 + r];
        #pragma unroll
        for (int i = 0; i < 4; ++i) acc[j][i] = bv;
    }

    #pragma unroll
    for (int ks = 0; ks < 8; ++ks) {
        int k0 = ks * 32 + q * 8;
        half8 a0 = *(const half8*)&Wh[(size_t)(o0 + w * 32 + mc) * CC + k0];
        half8 a1 = *(const half8*)&Wh[(size_t)(o0 + w * 32 + 16 + mc) * CC + k0];
        #pragma unroll
        for (int i = 0; i < 4; ++i) {
            half8 bfr = *(const half8*)&xTb[(size_t)(n0 + i * 16 + mc) * CC + k0];
            acc[0][i] = __builtin_amdgcn_mfma_f32_16x16x32_f16(a0, bfr, acc[0][i], 0, 0, 0);
            acc[1][i] = __builtin_amdgcn_mfma_f32_16x16x32_f16(a1, bfr, acc[1][i], 0, 0, 0);
        }
    }

    #pragma unroll
    for (int j = 0; j < 2; ++j)
        #pragma unroll
        for (int i = 0; i < 4; ++i)
            #pragma unroll
            for (int r = 0; r < 4; ++r) {
                int o = o0 + w * 32 + j * 16 + q * 4 + r;
                hb[(size_t)o * NN + n0 + i * 16 + mc] = (half_t)acc[j][i][r];
            }
}

// ---------------------------------------------------------------------------
// stats: Llog2[n] = -log2( sum_m exp(S[n,m]) ). grid (128, 4, 2).
// ---------------------------------------------------------------------------
__global__ __launch_bounds__(256)
void stats_kernel(const half_t* __restrict__ fT0, const half_t* __restrict__ gT0,
                  const half_t* __restrict__ fT1, const half_t* __restrict__ gT1,
                  float* __restrict__ L0, float* __restrict__ L1)
{
    __shared__ float red_l[4][32];
    const int b  = blockIdx.y;
    const int sel = blockIdx.z;
    const half_t* fT = sel ? fT1 : fT0;
    const half_t* gT = sel ? gT1 : gT0;
    float* Lout = sel ? L1 : L0;

    const int n0 = blockIdx.x * 32;
    const int t  = threadIdx.x;
    const int w = t >> 6, lane = t & 63, q = lane >> 4, mc = lane & 15;
    const half_t* fTb = fT + (size_t)b * NN * 32;
    const half_t* gTb = gT + (size_t)b * NN * 32;

    half8 a0 = *(const half8*)&fTb[(size_t)(n0 + mc) * 32 + q * 8];
    half8 a1 = *(const half8*)&fTb[(size_t)(n0 + 16 + mc) * 32 + q * 8];

    float l0[4] = {0.f, 0.f, 0.f, 0.f}, l1[4] = {0.f, 0.f, 0.f, 0.f};
    for (int it = 0; it < NN / 64; ++it) {
        int m = (it * 4 + w) * 16 + mc;
        half8 bfr = *(const half8*)&gTb[(size_t)m * 32 + q * 8];
        floatx4 S0 = __builtin_amdgcn_mfma_f32_16x16x32_f16(a0, bfr, (floatx4){0.f,0.f,0.f,0.f}, 0, 0, 0);
        floatx4 S1 = __builtin_amdgcn_mfma_f32_16x16x32_f16(a1, bfr, (floatx4){0.f,0.f,0.f,0.f}, 0, 0, 0);
        #pragma unroll
        for (int r = 0; r < 4; ++r) { l0[r] += __expf(S0[r]); l1[r] += __expf(S1[r]); }
    }
    #pragma unroll
    for (int r = 0; r < 4; ++r) {
        #pragma unroll
        for (int off = 1; off < 16; off <<= 1) {
            l0[r] += __shfl_xor(l0[r], off);
            l1[r] += __shfl_xor(l1[r], off);
        }
    }
    if (mc == 0)
        #pragma unroll
        for (int r = 0; r < 4; ++r) {
            red_l[w][q * 4 + r]      = l0[r];
            red_l[w][16 + q * 4 + r] = l1[r];
        }
    __syncthreads();
    if (t < 32) {
        float L = red_l[0][t] + red_l[1][t] + red_l[2][t] + red_l[3][t];
        Lout[(size_t)b * NN + n0 + t] = -log2f(L);
    }
}

// ---------------------------------------------------------------------------
// pv: out[c,m] = src[c,m] + gamma * sum_n h[c,n] * exp2(S*log2e + Llog2[n]).
// v5: P computed ONCE (no c-split duplication). grid (64, 8): block =
// 64 m x 256 c (full C), 8 waves, 512 thr, 2 blocks/CU. v1's proven
// 2-barrier single-buffer schedule, pitch-72 LDS, 1-ahead register prefetch.
// S phase: wave w -> m-group (w>>1)*16, n-half (w&1)*32: 2 MFMA16, 8 exp/ln.
// PV: wave w -> c-strip w*32, both 32-m strips: 8 MFMA32, 12 ds_read_b128.
// Epilogue: per-wave direct store (no cross-wave reduction).
// VGPR budget ~95 (acc[2]=32 + prefetch 32 + misc) -> no spill (R3 lesson).
// ---------------------------------------------------------------------------
__global__ __launch_bounds__(512, 4)
void pv_kernel(const half_t* __restrict__ fT0, const half_t* __restrict__ gT0,
               const half_t* __restrict__ h0, const float* __restrict__ L0,
               const float* __restrict__ src0, float* __restrict__ out0,
               const half_t* __restrict__ fT1, const half_t* __restrict__ gT1,
               const half_t* __restrict__ h1, const float* __restrict__ L1,
               const float* __restrict__ src1, float* __restrict__ out1,
               const float* __restrict__ gamma)
{
    __shared__ half_t h_lds[256][72];    // 36 KB, pitch 72 (v1-proven)
    __shared__ half_t PT[64][72];        // 9 KB, P^T[m][n]

    const int m0 = blockIdx.x * 64;
    const int b  = blockIdx.y & 3;
    const int sel = blockIdx.y >> 2;
    const half_t* fT = sel ? fT1 : fT0;
    const half_t* gT = sel ? gT1 : gT0;
    const half_t* h  = sel ? h1 : h0;
    const float*  Lg = sel ? L1 : L0;
    const float*  src = sel ? src1 : src0;
    float* out = sel ? out1 : out0;

    const int t = threadIdx.x;
    const int w = t >> 6, lane = t & 63;
    const int q = lane >> 4, mc = lane & 15;
    const int l5 = lane >> 5, l31 = lane & 31;

    const int mg  = (w >> 1) * 16;     // S-phase m-group (16 rows of 64)
    const int nhf = (w & 1) * 32;      // S-phase n-half (32 of 64)

    const half_t* fTb = fT + (size_t)b * NN * 32;
    const half_t* gTb = gT + (size_t)b * NN * 32;
    const half_t* hb  = h + (size_t)b * CC * NN;
    const float*  Lb  = Lg + (size_t)b * NN;

    // persistent S B-frag: m = m0 + mg + mc
    const half8 gS = *(const half8*)&gTb[(size_t)(m0 + mg + mc) * 32 + q * 8];

    // h staging: thread covers rows srow + 64*i (i=0..3), chunk sch
    const int srow = t >> 3;    // 0..63
    const int sch  = t & 7;     // 0..7

    // ---- prefetch tile 0
    half8 hpre[4]; half8 fpre[2]; float4 lv[2];
    #pragma unroll
    for (int i = 0; i < 4; ++i)
        hpre[i] = *(const half8*)&hb[(size_t)(srow + 64 * i) * NN + sch * 8];
    #pragma unroll
    for (int s = 0; s < 2; ++s) {
        fpre[s] = *(const half8*)&fTb[(size_t)(nhf + s * 16 + mc) * 32 + q * 8];
        lv[s]   = *(const float4*)&Lb[nhf + s * 16 + q * 4];
    }

    floatx16 acc[2];
    #pragma unroll
    for (int bm = 0; bm < 2; ++bm)
        #pragma unroll
        for (int r = 0; r < 16; ++r) acc[bm][r] = 0.f;

    for (int nt = 0; nt < NN; nt += 64) {
        __syncthreads();              // A: previous PV reads done
        #pragma unroll
        for (int i = 0; i < 4; ++i)
            *(half8*)&h_lds[srow + 64 * i][sch * 8] = hpre[i];

        // ---- S phase: wave's 16m x 32n strip -> PT (computed ONCE)
        #pragma unroll
        for (int s = 0; s < 2; ++s) {
            floatx4 S = __builtin_amdgcn_mfma_f32_16x16x32_f16(
                fpre[s], gS, (floatx4){0.f, 0.f, 0.f, 0.f}, 0, 0, 0);
            half4 p;
            p[0] = (half_t)exp2f(fmaf(S[0], 1.44269504f, lv[s].x));
            p[1] = (half_t)exp2f(fmaf(S[1], 1.44269504f, lv[s].y));
            p[2] = (half_t)exp2f(fmaf(S[2], 1.44269504f, lv[s].z));
            p[3] = (half_t)exp2f(fmaf(S[3], 1.44269504f, lv[s].w));
            *(half4*)&PT[mg + mc][nhf + s * 16 + q * 4] = p;
        }
        __syncthreads();              // B: PT/h_lds visible to all waves

        // ---- prefetch next tile (overlaps PV below)
        int ntn = nt + 64; if (ntn >= NN) ntn = 0;
        #pragma unroll
        for (int i = 0; i < 4; ++i)
            hpre[i] = *(const half8*)&hb[(size_t)(srow + 64 * i) * NN + ntn + sch * 8];
        #pragma unroll
        for (int s = 0; s < 2; ++s) {
            fpre[s] = *(const half8*)&fTb[(size_t)(ntn + nhf + s * 16 + mc) * 32 + q * 8];
            lv[s]   = *(const float4*)&Lb[ntn + nhf + s * 16 + q * 4];
        }

        // ---- PV: 4 k-chunks of 16; wave's 32c strip x both 32m strips
        #pragma unroll
        for (int ch = 0; ch < 4; ++ch) {
            half8 Ah = *(const half8*)&h_lds[w * 32 + l31][ch * 16 + l5 * 8];
            half8 B0 = *(const half8*)&PT[l31][ch * 16 + l5 * 8];
            half8 B1 = *(const half8*)&PT[32 + l31][ch * 16 + l5 * 8];
            acc[0] = __builtin_amdgcn_mfma_f32_32x32x16_f16(Ah, B0, acc[0], 0, 0, 0);
            acc[1] = __builtin_amdgcn_mfma_f32_32x32x16_f16(Ah, B1, acc[1], 0, 0, 0);
        }
    }

    // ---- epilogue: out = src + gamma * acc (D: col=l31->m, row pattern->c)
    const float gm = gamma[0];
    const float* srcb = src + (size_t)b * CC * NN;
    float* outb = out + (size_t)b * CC * NN;
    #pragma unroll
    for (int bm = 0; bm < 2; ++bm) {
        const int m = m0 + bm * 32 + l31;
        #pragma unroll
        for (int r = 0; r < 16; ++r) {
            int c = w * 32 + (r & 3) + 8 * (r >> 2) + 4 * l5;
            size_t idx = (size_t)c * NN + m;
            outb[idx] = fmaf(gm, acc[bm][r], srcb[idx]);
        }
    }
}

// ---------------------------------------------------------------------------
extern "C" void kernel_launch(void* const* d_in, const int* in_sizes, int n_in,
                              void* d_out, int out_size, void* d_ws, size_t ws_size,
                              hipStream_t stream)
{
    const float* x   = (const float*)d_in[0];
    const float* y   = (const float*)d_in[1];
    const float* Wfx = (const float*)d_in[2];
    const float* bfx = (const float*)d_in[3];
    const float* Wgx = (const float*)d_in[4];
    const float* bgx = (const float*)d_in[5];
    const float* Whx = (const float*)d_in[6];
    const float* bhx = (const float*)d_in[7];
    const float* Wfy = (const float*)d_in[8];
    const float* bfy = (const float*)d_in[9];
    const float* Wgy = (const float*)d_in[10];
    const float* bgy = (const float*)d_in[11];
    const float* Why = (const float*)d_in[12];
    const float* bhy = (const float*)d_in[13];
    const float* gam = (const float*)d_in[14];

    const size_t SZ_XT = (size_t)BB * NN * CC;   // 4,194,304 halves
    const size_t SZ_FG = (size_t)BB * NN * 32;   // 524,288 halves
    half_t* xTx   = (half_t*)d_ws;
    half_t* xTy   = xTx + SZ_XT;
    half_t* hx    = xTy + SZ_XT;
    half_t* hy    = hx + SZ_XT;
    half_t* fxT   = hy + SZ_XT;
    half_t* gxT   = fxT + SZ_FG;
    half_t* fyT   = gxT + SZ_FG;
    half_t* gyT   = fyT + SZ_FG;
    half_t* Wfx_h = gyT + SZ_FG;
    half_t* Wgx_h = Wfx_h + 32 * CC;
    half_t* Wfy_h = Wgx_h + 32 * CC;
    half_t* Wgy_h = Wfy_h + 32 * CC;
    half_t* Whx_h = Wgy_h + 32 * CC;
    half_t* Why_h = Whx_h + CC * CC;
    float*  Lx    = (float*)(Why_h + CC * CC);
    float*  Ly    = Lx + (size_t)BB * NN;

    float* outx = (float*)d_out;
    float* outy = outx + (size_t)BB * CC * NN;

    cvt_w_kernel<<<dim3(64, 6), 256, 0, stream>>>(Wfx, Wgx, Whx, Wfy, Wgy, Why,
                                                  Wfx_h, Wgx_h, Whx_h, Wfy_h, Wgy_h, Why_h);

    transpose_cvt_kernel<<<dim3(64, 4, 8), 256, 0, stream>>>(x, y, xTx, xTy);

    proj_fg_kernel<<<dim3(64, 4, 2), 256, 0, stream>>>(
        xTx, xTy, Wfx_h, Wgx_h, Wfy_h, Wgy_h, bfx, bgx, bfy, bgy, fxT, gxT, fyT, gyT);

    proj_h_kernel<<<dim3(64, 2, 8), 256, 0, stream>>>(
        xTx, xTy, Whx_h, Why_h, bhx, bhy, hx, hy);

    // att_x rows: fy vs gx -> Lx ; att_y rows: fx vs gy -> Ly
    stats_kernel<<<dim3(128, 4, 2), 256, 0, stream>>>(fyT, gxT, fxT, gyT, Lx, Ly);

    pv_kernel<<<dim3(64, 8), 512, 0, stream>>>(
        fyT, gxT, hx, Lx, x, outx,
        fxT, gyT, hy, Ly, y, outy, gam);
}